// Round 5
// baseline (33.023 us; speedup 1.0000x reference)
//
#include <hip/hip_runtime.h>

// messages: [B=64, E=4096, D=128] f32 ; tgt: [B,E] int32 in [0,N=512)
// out: [B, N, D] f32 segment-sum.
// Single fused kernel: each block owns (batch b, 64 output rows), bins its
// batch's indices in LDS, then gathers rows directly. No global atomics, no
// workspace, no inter-kernel round trips.
constexpr int B = 64, E = 4096, N = 512, D = 128;
constexpr int QN = 64;                 // segs owned per block
constexpr int THREADS = 512;           // 8 waves
constexpr int EPT = E / THREADS;       // 8 targets scanned per thread
constexpr int NBLK = B * (N / QN);     // 512 blocks

__global__ __launch_bounds__(THREADS)
void fused_seg_sum(const float* __restrict__ msgs,
                   const int* __restrict__ tgt,
                   float* __restrict__ out) {
    __shared__ int cnt[QN];               // counts -> placement cursors
    __shared__ int loff[QN + 1];          // exclusive offsets
    __shared__ unsigned short lst[E];     // seg-sorted edge ids (full capacity)

    const int tid  = threadIdx.x;
    const int lane = tid & 63;
    const int w    = tid >> 6;            // wave 0..7
    const int b    = blockIdx.x >> 3;     // 8 blocks per batch
    const int n0   = (blockIdx.x & 7) * QN;

    if (tid < QN) cnt[tid] = 0;
    __syncthreads();

    // ---- pass 1: scan batch indices (coalesced), count ours ----
    const int* tb = tgt + b * E;
    int tn[EPT];
    #pragma unroll
    for (int t = 0; t < EPT; ++t) {
        tn[t] = tb[t * THREADS + tid] - n0;
        if ((unsigned)tn[t] < (unsigned)QN) atomicAdd(&cnt[tn[t]], 1);
    }
    __syncthreads();

    // ---- exclusive scan of 64 counters (wave 0, one per lane) ----
    if (w == 0) {
        const int c = cnt[lane];
        int x = c;
        #pragma unroll
        for (int d = 1; d < 64; d <<= 1) {
            const int y = __shfl_up(x, d);
            if (lane >= d) x += y;
        }
        const int excl = x - c;
        loff[lane] = excl;
        cnt[lane]  = excl;                // becomes placement cursor
        if (lane == 63) loff[QN] = x;
    }
    __syncthreads();

    // ---- pass 2: place matched edge ids (LDS atomics only) ----
    #pragma unroll
    for (int t = 0; t < EPT; ++t) {
        if ((unsigned)tn[t] < (unsigned)QN) {
            const int pos = atomicAdd(&cnt[tn[t]], 1);
            lst[pos] = (unsigned short)(t * THREADS + tid);
        }
    }
    __syncthreads();

    // ---- gather: wave w handles segs n0 + w*8 .. n0 + w*8+7 ----
    const float2* mb = reinterpret_cast<const float2*>(msgs) + (size_t)b * E * 64;
    float2* ob = reinterpret_cast<float2*>(out) + ((size_t)b * N + n0) * 64;
    #pragma unroll
    for (int s = 0; s < 8; ++s) {
        const int n    = w * 8 + s;
        const int base = loff[n];
        const int k    = loff[n + 1] - base;
        float ax = 0.f, ay = 0.f;
        for (int i = 0; i < k; i += 8) {          // one iter for typical k<=8
            int ee[8]; float wt[8];
            #pragma unroll
            for (int j = 0; j < 8; ++j) {
                const bool v = (i + j < k);       // wave-uniform
                ee[j] = v ? (int)lst[base + i + j] : 0;   // LDS broadcast
                wt[j] = v ? 1.f : 0.f;
            }
            float2 vv[8];
            #pragma unroll
            for (int j = 0; j < 8; ++j)           // 8 independent 512B loads
                vv[j] = mb[(size_t)ee[j] * 64 + lane];
            #pragma unroll
            for (int j = 0; j < 8; ++j) { ax += wt[j] * vv[j].x; ay += wt[j] * vv[j].y; }
        }
        float2 r; r.x = ax; r.y = ay;
        ob[(size_t)n * 64 + lane] = r;            // covers every output once
    }
}

extern "C" void kernel_launch(void* const* d_in, const int* in_sizes, int n_in,
                              void* d_out, int out_size, void* d_ws, size_t ws_size,
                              hipStream_t stream) {
    const float* msgs = (const float*)d_in[0];
    const int*   tgt  = (const int*)d_in[1];
    float* out = (float*)d_out;
    fused_seg_sum<<<NBLK, THREADS, 0, stream>>>(msgs, tgt, out);
}